// Round 4
// baseline (1433.474 us; speedup 1.0000x reference)
//
#include <hip/hip_runtime.h>

#define NF 8192
#define KN 48
#define TM 16

typedef __attribute__((ext_vector_type(8))) short short8;
typedef __attribute__((ext_vector_type(4))) float f32x4;

__device__ __forceinline__ unsigned short bf16e(float f) {
    return (unsigned short)((__float_as_uint(f) + 0x8000u) >> 16);
}
__device__ __forceinline__ float bf16d(unsigned hb) { return __uint_as_float(hb << 16); }

// ---------------------------------------------------------------------------
// geometry: ball->cube + trilinear corner weights for one neighbor
// packs 8 entries of (tap<<16 | bf16(weight)) into g[0..7]
// ---------------------------------------------------------------------------
__device__ __forceinline__ void pn_geom(float rx, float ry, float rz, unsigned* g)
{
    float d2  = rx * rx + ry * ry + rz * rz;
    float om  = 1.0f - d2;
    float win = om * om * om;
    win = fminf(fmaxf(win, 0.0f), 1.0f);

    float rxy2 = rx * rx + ry * ry;
    float rho  = sqrtf(rxy2 + rz * rz + 1e-8f);
    float rxyv = sqrtf(rxy2 + 1e-8f);
    bool  pole = (rxy2 <= 1.25f * rz * rz);
    float s    = pole ? sqrtf(3.0f * rho / (rho + fabsf(rz))) : (rho / rxyv);
    float cx = rx * s, cy = ry * s;
    float sgnz = (rz > 0.0f) ? 1.0f : ((rz < 0.0f) ? -1.0f : 0.0f);
    float cz   = pole ? sgnz * rho : 1.5f * rz;

    float rr   = sqrtf(cx * cx + cy * cy + 1e-8f);
    bool  cond = fabsf(cx) >= fabsf(cy);
    float sx = (cx >= 0.0f) ? 1.0f : -1.0f;
    float sy = (cy >= 0.0f) ? 1.0f : -1.0f;
    float safecx = (fabsf(cx) > 1e-8f) ? cx : 1.0f;
    float safecy = (fabsf(cy) > 1e-8f) ? cy : 1.0f;
    const float C4PI = 1.2732395447351628f;
    float u = cond ? (sx * rr) : (sy * C4PI * rr * atanf(cx / safecy));
    float v = cond ? (sx * C4PI * rr * atanf(cy / safecx)) : (sy * rr);
    if (rho < 1e-6f) { u = 0.0f; v = 0.0f; cz = 0.0f; }

    float tx = fminf(fmaxf((u  * 0.5f + 0.5f) * 3.0f, 0.0f), 3.0f);
    float ty = fminf(fmaxf((v  * 0.5f + 0.5f) * 3.0f, 0.0f), 3.0f);
    float tz = fminf(fmaxf((cz * 0.5f + 0.5f) * 3.0f, 0.0f), 3.0f);
    int ix = (int)floorf(tx); ix = ix < 0 ? 0 : (ix > 2 ? 2 : ix);
    int iy = (int)floorf(ty); iy = iy < 0 ? 0 : (iy > 2 ? 2 : iy);
    int iz = (int)floorf(tz); iz = iz < 0 ? 0 : (iz > 2 ? 2 : iz);
    float fx = tx - (float)ix, fy = ty - (float)iy, fz = tz - (float)iz;
    float wx0 = 1.0f - fx, wy0 = 1.0f - fy, wz0 = 1.0f - fz;

#pragma unroll
    for (int dx = 0; dx < 2; ++dx)
#pragma unroll
        for (int dy = 0; dy < 2; ++dy)
#pragma unroll
            for (int dz = 0; dz < 2; ++dz) {
                float w = (dx ? fx : wx0) * (dy ? fy : wy0) * (dz ? fz : wz0) * win;
                int tap = ((ix + dx) << 4) + ((iy + dy) << 2) + (iz + dz);
                g[(dx << 2) | (dy << 1) | dz] = ((unsigned)tap << 16) | (unsigned)bf16e(w);
            }
}

// ---------------------------------------------------------------------------
// prep: vel_new/pos_new, fluid feats, neighbor count, dense d0 branch
// ---------------------------------------------------------------------------
__global__ void __launch_bounds__(256) pn_prep(
    const float* __restrict__ pos, const float* __restrict__ vel,
    const int* __restrict__ nbrf,
    const float* __restrict__ d0w, const float* __restrict__ d0b,
    float* __restrict__ pos_new, float* __restrict__ feats0,
    float* __restrict__ X, float* __restrict__ nfn)
{
    int t = blockIdx.x * 256 + threadIdx.x;
    if (t >= NF) return;
    float vx = vel[t * 3 + 0], vy = vel[t * 3 + 1], vz = vel[t * 3 + 2];
    float vnx = vx, vny = vy - 9.81f * 0.02f, vnz = vz;
    float pnx = pos[t * 3 + 0] + (vx + vnx) * 0.01f;
    float pny = pos[t * 3 + 1] + (vy + vny) * 0.01f;
    float pnz = pos[t * 3 + 2] + (vz + vnz) * 0.01f;
    pos_new[t * 3 + 0] = pnx; pos_new[t * 3 + 1] = pny; pos_new[t * 3 + 2] = pnz;
    feats0[t * 4 + 0] = 1.0f; feats0[t * 4 + 1] = vnx;
    feats0[t * 4 + 2] = vny;  feats0[t * 4 + 3] = vnz;
    int cnt = 0;
    for (int k = 0; k < KN; ++k) cnt += (nbrf[t * KN + k] >= 0) ? 1 : 0;
    nfn[t] = (float)cnt;
    for (int j = 0; j < 32; ++j) {
        float s = d0b[j] + d0w[0 * 32 + j] + vnx * d0w[1 * 32 + j]
                + vny * d0w[2 * 32 + j] + vnz * d0w[3 * 32 + j];
        X[t * 96 + 64 + j] = s;
    }
}

// ---------------------------------------------------------------------------
// pack filter transposed bf16: FT[d][ch][t][c]  (d-major, K contiguous)
// t==64 row = dense weights when HAS_SELF; rows/chans beyond real = 0.
// ---------------------------------------------------------------------------
template <int CIN, int COUT, int CHUNK, int ROWS_P, int HAS_SELF>
__global__ void __launch_bounds__(256) pn_pack(
    const float* __restrict__ cw, const float* __restrict__ dw,
    const float* __restrict__ cb, const float* __restrict__ db,
    unsigned short* __restrict__ FT, float* __restrict__ B)
{
    constexpr int NCH  = (CIN + CHUNK - 1) / CHUNK;
    constexpr int AK   = ROWS_P * CHUNK;
    constexpr int KTOT = NCH * AK;
    constexpr int DPAD = ((COUT + 15) / 16) * 16;
    int i = blockIdx.x * 256 + threadIdx.x;
    if (i < DPAD * KTOT) {
        int d  = i / KTOT;
        int r  = i - d * KTOT;
        int ch = r / AK; r -= ch * AK;
        int t  = r / CHUNK;
        int c  = r - t * CHUNK;
        int cin = ch * CHUNK + c;
        float v = 0.0f;
        if (d < COUT && cin < CIN) {
            if (t < 64)                    v = cw[((size_t)t * CIN + cin) * COUT + d];
            else if (HAS_SELF && t == 64)  v = dw[(size_t)cin * COUT + d];
        }
        FT[i] = bf16e(v);
    }
    if (i < COUT) B[i] = cb[i] + (HAS_SELF ? db[i] : 0.0f);
}

// ---------------------------------------------------------------------------
// fused CConv: CSR build -> flat balanced A-build -> bf16 MFMA tap-GEMM
// OUT_MODE: 0 = X-slice, 1 = plain [NF][COUT], 2 = +resid, 3 = final pos/vel
// ---------------------------------------------------------------------------
template <int CIN, int COUT, int CHUNK, int ROWS_P, int HAS_SELF, int RELU_IN, int OUT_MODE>
__global__ void __launch_bounds__(512) pn_cconv(
    const float* __restrict__ qpos, const float* __restrict__ ppos,
    const float* __restrict__ feats, const int* __restrict__ nbr,
    const unsigned short* __restrict__ F2t, const float* __restrict__ bias,
    const float* __restrict__ resid, float* __restrict__ outp,
    const float* __restrict__ pos0, int out_stride, int out_off)
{
    constexpr int NCH    = (CIN + CHUNK - 1) / CHUNK;
    constexpr int AK     = ROWS_P * CHUNK;        // K per chunk (multiple of 32)
    constexpr int AKP    = AK + 8;                // padded LDS stride (elems)
    constexpr int KTOT   = NCH * AK;
    constexpr int S      = AK / 32;               // K-steps per chunk
    constexpr int DPAD   = ((COUT + 15) / 16) * 16;
    constexpr int NT     = DPAD / 16;             // d-tiles
    constexpr int SPLITK = 8 / NT;
    constexpr int SPC    = (S + SPLITK - 1) / SPLITK;
    constexpr int NGRP   = 512 / CHUNK;           // entry groups
    constexpr int NW     = 8 * AK;                // packed u32 words (16 pts * AK/2)
    constexpr int NR     = (NW + 511) / 512;

    __shared__ int      sI[TM * KN];
    __shared__ int      sKN[TM];
    __shared__ unsigned sEnt[TM * 384];
    __shared__ int      sCur[TM * 64];
    __shared__ __align__(16) char  sUbuf[TM * KN * 8 * 4]; // sG u32[TM][48][8] then sF bf16[TM][48][CHUNK]
    __shared__ __align__(16) float sA32[TM * AK];          // aliased as sAb bf16[TM][AKP]
    __shared__ float    sEpi[8 * 64 * 4];

    unsigned*       sG   = (unsigned*)sUbuf;
    unsigned short* sF   = (unsigned short*)sUbuf;
    unsigned short* sAb  = (unsigned short*)sA32;
    unsigned*       sAbw = (unsigned*)sA32;

    const int tid  = threadIdx.x;
    const int w    = tid >> 6;
    const int lane = tid & 63;
    const int pt0  = blockIdx.x * TM;

    if (tid < TM) sKN[tid] = KN;
    for (int i = tid; i < TM * 64; i += 512) sCur[i] = 0;
    __syncthreads();

    // phase 0: geometry into sG + per-tap counts
    for (int e = tid; e < TM * KN; e += 512) {
        int lp = e / KN, k = e - lp * KN;
        int q  = pt0 + lp;
        int id = nbr[q * KN + k];
        if (id >= 0) {
            sI[e] = id;
            float rx = (ppos[id * 3 + 0] - qpos[q * 3 + 0]) * (1.0f / 0.1125f);
            float ry = (ppos[id * 3 + 1] - qpos[q * 3 + 1]) * (1.0f / 0.1125f);
            float rz = (ppos[id * 3 + 2] - qpos[q * 3 + 2]) * (1.0f / 0.1125f);
            unsigned g[8];
            pn_geom(rx, ry, rz, g);
#pragma unroll
            for (int j = 0; j < 8; ++j) {
                sG[e * 8 + j] = g[j];
                atomicAdd(&sCur[lp * 64 + (g[j] >> 16)], 1);
            }
        } else {
            atomicMin(&sKN[lp], k);
        }
    }
    __syncthreads();

    // exclusive prefix over 64 taps per point (lanes = taps)
    for (int lp = w; lp < TM; lp += 8) {
        int v = sCur[lp * 64 + lane];
        int incl = v;
#pragma unroll
        for (int d = 1; d < 64; d <<= 1) {
            int t = __shfl_up(incl, (unsigned)d, 64);
            if (lane >= d) incl += t;
        }
        sCur[lp * 64 + lane] = incl - v;
    }
    __syncthreads();

    // fill tap-sorted entries: tap<<22 | k<<16 | bf16(w)
    for (int e = tid; e < TM * KN; e += 512) {
        int lp = e / KN, k = e - lp * KN;
        if (k < sKN[lp]) {
#pragma unroll
            for (int j = 0; j < 8; ++j) {
                unsigned u = sG[e * 8 + j];
                int tap = (int)(u >> 16);
                int p   = atomicAdd(&sCur[lp * 64 + tap], 1);
                sEnt[lp * 384 + p] = ((unsigned)tap << 22) | ((unsigned)k << 16) | (u & 0xffffu);
            }
        }
    }
    __syncthreads();   // sEnt ready; sG dead (sF may overwrite)

    f32x4 acc = {0.0f, 0.0f, 0.0f, 0.0f};

    for (int ch = 0; ch < NCH; ++ch) {
        const int cb0 = ch * CHUNK;

        // zero A (fp32) + stage neighbor feature chunk to bf16 LDS
        {
            f32x4 z = {0.0f, 0.0f, 0.0f, 0.0f};
            for (int i = tid; i < TM * AK / 4; i += 512) ((f32x4*)sA32)[i] = z;
        }
        for (int e = tid; e < TM * KN; e += 512) {
            int lp = e / KN, k = e - lp * KN;
            if (k < sKN[lp]) {
                int id = sI[e];
                unsigned short* dst = sF + e * CHUNK;
                if constexpr (CHUNK == 16) {
                    const float4* s4 = (const float4*)(feats + (size_t)id * CIN + cb0);
                    float4 f0 = s4[0], f1 = s4[1], f2 = s4[2], f3 = s4[3];
                    if (RELU_IN) {
                        f0.x=fmaxf(f0.x,0.f); f0.y=fmaxf(f0.y,0.f); f0.z=fmaxf(f0.z,0.f); f0.w=fmaxf(f0.w,0.f);
                        f1.x=fmaxf(f1.x,0.f); f1.y=fmaxf(f1.y,0.f); f1.z=fmaxf(f1.z,0.f); f1.w=fmaxf(f1.w,0.f);
                        f2.x=fmaxf(f2.x,0.f); f2.y=fmaxf(f2.y,0.f); f2.z=fmaxf(f2.z,0.f); f2.w=fmaxf(f2.w,0.f);
                        f3.x=fmaxf(f3.x,0.f); f3.y=fmaxf(f3.y,0.f); f3.z=fmaxf(f3.z,0.f); f3.w=fmaxf(f3.w,0.f);
                    }
                    uint4 pa, pb;
                    pa.x = (unsigned)bf16e(f0.x) | ((unsigned)bf16e(f0.y) << 16);
                    pa.y = (unsigned)bf16e(f0.z) | ((unsigned)bf16e(f0.w) << 16);
                    pa.z = (unsigned)bf16e(f1.x) | ((unsigned)bf16e(f1.y) << 16);
                    pa.w = (unsigned)bf16e(f1.z) | ((unsigned)bf16e(f1.w) << 16);
                    pb.x = (unsigned)bf16e(f2.x) | ((unsigned)bf16e(f2.y) << 16);
                    pb.y = (unsigned)bf16e(f2.z) | ((unsigned)bf16e(f2.w) << 16);
                    pb.z = (unsigned)bf16e(f3.x) | ((unsigned)bf16e(f3.y) << 16);
                    pb.w = (unsigned)bf16e(f3.z) | ((unsigned)bf16e(f3.w) << 16);
                    ((uint4*)dst)[0] = pa;
                    ((uint4*)dst)[1] = pb;
                } else if constexpr (CIN >= 4) {
                    float4 f = *(const float4*)(feats + (size_t)id * CIN + cb0);
                    if (RELU_IN) { f.x=fmaxf(f.x,0.f); f.y=fmaxf(f.y,0.f); f.z=fmaxf(f.z,0.f); f.w=fmaxf(f.w,0.f); }
                    uint2 p;
                    p.x = (unsigned)bf16e(f.x) | ((unsigned)bf16e(f.y) << 16);
                    p.y = (unsigned)bf16e(f.z) | ((unsigned)bf16e(f.w) << 16);
                    *((uint2*)dst) = p;
                } else { // CIN == 3
                    float f0 = feats[(size_t)id * 3 + 0];
                    float f1 = feats[(size_t)id * 3 + 1];
                    float f2 = feats[(size_t)id * 3 + 2];
                    uint2 p;
                    p.x = (unsigned)bf16e(f0) | ((unsigned)bf16e(f1) << 16);
                    p.y = (unsigned)bf16e(f2);
                    *((uint2*)dst) = p;
                }
            }
        }
        __syncthreads();

        // A-build: flat balanced entry ranges, run-accumulate, atomic flush
        {
            const int g = tid / CHUNK;
            const int c = tid - g * CHUNK;
            for (int lp = 0; lp < TM; ++lp) {
                const int n8  = sKN[lp] * 8;
                const int EPG = (n8 + NGRP - 1) / NGRP;
                int e  = g * EPG;
                int e1 = min(n8, e + EPG);
                float a = 0.0f;
                int cur = -1;
                for (; e < e1; ++e) {
                    unsigned u = sEnt[lp * 384 + e];
                    int tap  = (int)(u >> 22);
                    int k    = (int)((u >> 16) & 63u);
                    float wg = bf16d(u & 0xffffu);
                    float f  = bf16d((unsigned)sF[(lp * KN + k) * CHUNK + c]);
                    if (tap != cur) {
                        if (cur >= 0) atomicAdd(&sA32[(lp * ROWS_P + cur) * CHUNK + c], a);
                        a = 0.0f; cur = tap;
                    }
                    a = fmaf(wg, f, a);
                }
                if (cur >= 0) atomicAdd(&sA32[(lp * ROWS_P + cur) * CHUNK + c], a);
            }
        }
        __syncthreads();

        // convert fp32 A -> bf16 packed (self row injected), two-pass for alias
        unsigned tmp[NR];
#pragma unroll
        for (int i = 0; i < NR; ++i) {
            int idx = tid + i * 512;
            if (idx < NW) {
                int pt = idx / (AK / 2);
                int kw = idx - pt * (AK / 2);
                int k0 = kw * 2;
                float f0, f1;
                if (HAS_SELF && (k0 / CHUNK) == 64) {
                    int cc = k0 - 64 * CHUNK;
                    const float* sp = feats + (size_t)(pt0 + pt) * CIN + cb0 + cc;
                    f0 = sp[0]; f1 = sp[1];
                    if (RELU_IN) { f0 = fmaxf(f0, 0.f); f1 = fmaxf(f1, 0.f); }
                } else {
                    f0 = sA32[pt * AK + k0];
                    f1 = sA32[pt * AK + k0 + 1];
                }
                tmp[i] = (unsigned)bf16e(f0) | ((unsigned)bf16e(f1) << 16);
            }
        }
        __syncthreads();
#pragma unroll
        for (int i = 0; i < NR; ++i) {
            int idx = tid + i * 512;
            if (idx < NW) {
                int pt = idx / (AK / 2);
                int kw = idx - pt * (AK / 2);
                sAbw[pt * (AKP / 2) + kw] = tmp[i];
            }
        }
        __syncthreads();

        // MFMA tap-GEMM: out[16 pts][DPAD] += A[16][AK] * F[AK][DPAD]
        {
            const int dt = w % NT, kh = w / NT;
            const int n  = lane & 15, kg = lane >> 4;
            const int drow = dt * 16 + n;
            const unsigned short* gB = F2t + (size_t)drow * KTOT + ch * AK;
            const int s0 = kh * SPC;
            const int s1 = min(S, s0 + SPC);
            for (int s = s0; s < s1; ++s) {
                int kidx = s * 32 + kg * 8;
                short8 av = *(const short8*)(sAb + (lane & 15) * AKP + kidx);
                short8 bv = *(const short8*)(gB + kidx);
                acc = __builtin_amdgcn_mfma_f32_16x16x32_bf16(av, bv, acc, 0, 0, 0);
            }
        }
        __syncthreads();   // protect sAb/sA32/sF before next chunk rewrites
    }

    // epilogue: split-K combine + bias + output modes
#pragma unroll
    for (int r = 0; r < 4; ++r) sEpi[(w * 64 + lane) * 4 + r] = acc[r];
    __syncthreads();

    if (w < NT) {
        float sum[4];
#pragma unroll
        for (int r = 0; r < 4; ++r) {
            float s = 0.0f;
#pragma unroll
            for (int kh = 0; kh < SPLITK; ++kh)
                s += sEpi[((kh * NT + w) * 64 + lane) * 4 + r];
            sum[r] = s;
        }
        int d = w * 16 + (lane & 15);
        if (d < COUT) {
            float b = bias[d];
#pragma unroll
            for (int r = 0; r < 4; ++r) {
                int pt = (lane >> 4) * 4 + r;
                int q  = pt0 + pt;
                float y = sum[r] + b;
                if constexpr (OUT_MODE == 0) {
                    outp[q * out_stride + out_off + d] = y;
                } else if constexpr (OUT_MODE == 1) {
                    outp[q * COUT + d] = y;
                } else if constexpr (OUT_MODE == 2) {
                    outp[q * COUT + d] = y + resid[q * COUT + d];
                } else {
                    float corr = y * (1.0f / 128.0f);
                    float pn   = qpos[q * 3 + d];
                    float pc   = pn + corr;
                    outp[q * 3 + d]          = pc;
                    outp[NF * 3 + q * 3 + d] = (pc - pos0[q * 3 + d]) * (1.0f / 0.02f);
                }
            }
        }
    }
}

// ---------------------------------------------------------------------------
// host launcher
// ---------------------------------------------------------------------------
extern "C" void kernel_launch(void* const* d_in, const int* in_sizes, int n_in,
                              void* d_out, int out_size, void* d_ws, size_t ws_size,
                              hipStream_t stream)
{
    (void)in_sizes; (void)n_in; (void)out_size; (void)ws_size;

    const float* pos       = (const float*)d_in[0];
    const float* vel       = (const float*)d_in[1];
    const float* box       = (const float*)d_in[2];
    const float* box_feats = (const float*)d_in[3];
    const int*   nbrf      = (const int*)d_in[4];
    const int*   nbrb      = (const int*)d_in[5];
    const float* cf0_w = (const float*)d_in[6];
    const float* cf0_b = (const float*)d_in[7];
    const float* co0_w = (const float*)d_in[8];
    const float* co0_b = (const float*)d_in[9];
    const float* d0_w  = (const float*)d_in[10];
    const float* d0_b  = (const float*)d_in[11];
    const float* c1_w  = (const float*)d_in[12];
    const float* c1_b  = (const float*)d_in[13];
    const float* d1_w  = (const float*)d_in[14];
    const float* d1_b  = (const float*)d_in[15];
    const float* c2_w  = (const float*)d_in[16];
    const float* c2_b  = (const float*)d_in[17];
    const float* d2_w  = (const float*)d_in[18];
    const float* d2_b  = (const float*)d_in[19];
    const float* c3_w  = (const float*)d_in[20];
    const float* c3_b  = (const float*)d_in[21];
    const float* d3_w  = (const float*)d_in[22];
    const float* d3_b  = (const float*)d_in[23];

    char* ws = (char*)d_ws;
    float*          POSNEW = (float*)(ws + 0);        // 98304
    float*          FEATS0 = (float*)(ws + 98304);    // 131072
    float*          X      = (float*)(ws + 229376);   // 8192*96*4 = 3145728
    float*          X1     = (float*)(ws + 3375104);  // 2097152
    float*          X2     = (float*)(ws + 5472256);  // 2097152
    unsigned short* FT1    = (unsigned short*)(ws + 7569408); // 64*6336*2 = 811008
    unsigned short* FT2    = (unsigned short*)(ws + 8380416); // 64*4224*2 = 540672
    unsigned short* FT3    = (unsigned short*)(ws + 8921088); // 16*4224*2 = 135168
    unsigned short* FTf0   = (unsigned short*)(ws + 9056256); // 32*288*2  = 18432
    unsigned short* FTo0   = (unsigned short*)(ws + 9074688); // 32*288*2  = 18432
    float*          B1     = (float*)(ws + 9093120);
    float*          B2     = (float*)(ws + 9093376);
    float*          B3     = (float*)(ws + 9093632);
    float*          Bf0    = (float*)(ws + 9093888);
    float*          Bo0    = (float*)(ws + 9094144);

    float* out_f = (float*)d_out;

    // packs: <CIN, COUT, CHUNK, ROWS_P, HAS_SELF>
    pn_pack<96, 64, 16, 66, 1><<<(64 * 6336 + 255) / 256, 256, 0, stream>>>(c1_w, d1_w, c1_b, d1_b, FT1, B1);
    pn_pack<64, 64, 16, 66, 1><<<(64 * 4224 + 255) / 256, 256, 0, stream>>>(c2_w, d2_w, c2_b, d2_b, FT2, B2);
    pn_pack<64, 3, 16, 66, 1><<<(16 * 4224 + 255) / 256, 256, 0, stream>>>(c3_w, d3_w, c3_b, d3_b, FT3, B3);
    pn_pack<4, 32, 4, 72, 0><<<(32 * 288 + 255) / 256, 256, 0, stream>>>(cf0_w, nullptr, cf0_b, nullptr, FTf0, Bf0);
    pn_pack<3, 32, 4, 72, 0><<<(32 * 288 + 255) / 256, 256, 0, stream>>>(co0_w, nullptr, co0_b, nullptr, FTo0, Bo0);

    pn_prep<<<(NF + 255) / 256, 256, 0, stream>>>(pos, vel, nbrf, d0_w, d0_b,
                                                  POSNEW, FEATS0, X, out_f + NF * 6);

    // convs: <CIN, COUT, CHUNK, ROWS_P, HAS_SELF, RELU_IN, OUT_MODE>, grid NF/16, 512 thr
    pn_cconv<4, 32, 4, 72, 0, 0, 0><<<NF / TM, 512, 0, stream>>>(
        POSNEW, POSNEW, FEATS0, nbrf, FTf0, Bf0, nullptr, X, nullptr, 96, 32);
    pn_cconv<3, 32, 4, 72, 0, 0, 0><<<NF / TM, 512, 0, stream>>>(
        POSNEW, box, box_feats, nbrb, FTo0, Bo0, nullptr, X, nullptr, 96, 0);
    pn_cconv<96, 64, 16, 66, 1, 1, 1><<<NF / TM, 512, 0, stream>>>(
        POSNEW, POSNEW, X, nbrf, FT1, B1, nullptr, X1, nullptr, 0, 0);
    pn_cconv<64, 64, 16, 66, 1, 1, 2><<<NF / TM, 512, 0, stream>>>(
        POSNEW, POSNEW, X1, nbrf, FT2, B2, X1, X2, nullptr, 0, 0);
    pn_cconv<64, 3, 16, 66, 1, 1, 3><<<NF / TM, 512, 0, stream>>>(
        POSNEW, POSNEW, X2, nbrf, FT3, B3, nullptr, out_f, pos, 0, 0);
}